// Round 13
// baseline (46.937 us; speedup 1.0000x reference)
//
#include <hip/hip_runtime.h>
#include <hip/hip_bf16.h>
#include <climits>

#define NATOMS 50000
#define NEDGES 100000
#define AD 64
#define BD 16
#define PITCH 1096            // LDS row pitch in bf16 elems (1088 + 8)
#define NR ((NEDGES + 31) / 32)   // 3125 aligned 32-edge windows
#define NBANDS 256
#define NWAVES 8              // 512 thr, 1 block/CU, 2 waves/SIMD -> 256 reg budget
#define NWIN (2 * NWAVES)     // wave w owns windows 2w and 2w+1 (nW <= 14)

typedef __bf16 bf16x8 __attribute__((ext_vector_type(8)));
typedef __bf16 bf16x4 __attribute__((ext_vector_type(4)));
typedef float  f32x16 __attribute__((ext_vector_type(16)));

__global__ __launch_bounds__(256)
void zero_out(float4* __restrict__ out, int n4) {
    const int stride = gridDim.x * blockDim.x;
    const float4 z = make_float4(0.f, 0.f, 0.f, 0.f);
    for (int i = blockIdx.x * blockDim.x + threadIdx.x; i < n4; i += stride)
        out[i] = z;
}

// Dual first_break: smallest break index >= p0 and >= p1, loads overlapped.
// Break: q==0, q==NEDGES, or tgt[q]!=tgt[q-1].
__device__ __forceinline__ void first_break2(const int* __restrict__ pair,
                                             int p0, int p1, const int lane,
                                             int& s, int& e) {
    const int qa = p0 + lane;
    const int qb = p1 + lane;
    const bool ba = (qa == 0 || qa >= NEDGES) ? true : (pair[2 * qa] != pair[2 * qa - 2]);
    const bool bb = (qb == 0 || qb >= NEDGES) ? true : (pair[2 * qb] != pair[2 * qb - 2]);
    const unsigned long long ma = __ballot(ba);
    const unsigned long long mb = __ballot(bb);

    if (ma) { s = p0 + (int)__builtin_ctzll(ma); if (s > NEDGES) s = NEDGES; }
    else {
        int p = p0 + 64;
        while (true) {
            const int q = p + lane;
            const bool bk = (q >= NEDGES) ? true : (pair[2 * q] != pair[2 * q - 2]);
            const unsigned long long m = __ballot(bk);
            if (m) { s = p + (int)__builtin_ctzll(m); if (s > NEDGES) s = NEDGES; break; }
            p += 64;
        }
    }
    if (mb) { e = p1 + (int)__builtin_ctzll(mb); if (e > NEDGES) e = NEDGES; }
    else {
        int p = p1 + 64;
        while (true) {
            const int q = p + lane;
            const bool bk = (q >= NEDGES) ? true : (pair[2 * q] != pair[2 * q - 2]);
            const unsigned long long m = __ballot(bk);
            if (m) { e = p + (int)__builtin_ctzll(m); if (e > NEDGES) e = NEDGES; break; }
            p += 64;
        }
    }
}

// Gather chunk inputs for window [g, g+32) ∩ [, e): nbr half-row, bond row, tgt.
// Inactive windows (e <= g): all lanes load row 0 (defined), tgt = INT_MAX.
__device__ __forceinline__ void load_chunk(
    const int g, const int e, const int l31, const int h8,
    const float* __restrict__ atom, const float* __restrict__ bond,
    const int* __restrict__ pair,
    float nb[4][8], float bd[16], int& myTgt)
{
    const int eA = g + l31;
    const bool validE = (eA < e);
    const int eAc = validE ? eA : 0;

    int ni = pair[2 * eAc + 1];
    if ((unsigned)ni >= NATOMS) ni = 0;
    const float* nbrRow  = atom + (long)ni * AD;
    const float* bondRow = bond + (long)eAc * BD;

    #pragma unroll
    for (int q = 0; q < 4; ++q) {
        const float4 lo = *reinterpret_cast<const float4*>(nbrRow + q * 16 + h8);
        const float4 hi = *reinterpret_cast<const float4*>(nbrRow + q * 16 + h8 + 4);
        nb[q][0] = lo.x; nb[q][1] = lo.y; nb[q][2] = lo.z; nb[q][3] = lo.w;
        nb[q][4] = hi.x; nb[q][5] = hi.y; nb[q][6] = hi.z; nb[q][7] = hi.w;
    }
    #pragma unroll
    for (int q = 0; q < 4; ++q) {
        const float4 v = *reinterpret_cast<const float4*>(bondRow + q * 4);
        bd[q * 4 + 0] = v.x; bd[q * 4 + 1] = v.y;
        bd[q * 4 + 2] = v.z; bd[q * 4 + 3] = v.w;
    }
    myTgt = validE ? pair[2 * eA] : INT_MAX;
}

// Segmented inclusive scan over sorted tgt within the 32-lane group.
// Steps 1,2,4 always; steps 8,16 only if some segment length >= 9.
__device__ __forceinline__ bool scan_pair(
    f32x16& acc0, f32x16& acc1, const int myTgt, const int l31, const int w)
{
    #pragma unroll
    for (int d = 1; d <= 4; d <<= 1) {
        const int srcTgt = __shfl_up(myTgt, (unsigned)d, 32);
        const bool same = (l31 >= d) && (srcTgt == myTgt);
        #pragma unroll
        for (int r = 0; r < 16; ++r) {
            const float v0 = __shfl_up(acc0[r], (unsigned)d, 32);
            const float v1 = __shfl_up(acc1[r], (unsigned)d, 32);
            if (same) { acc0[r] += v0; acc1[r] += v1; }
        }
    }
    const int src8 = __shfl_up(myTgt, 8u, 32);
    if (__any((l31 >= 8) && (src8 == myTgt))) {
        const bool same8 = (l31 >= 8) && (src8 == myTgt);
        #pragma unroll
        for (int r = 0; r < 16; ++r) {
            const float v0 = __shfl_up(acc0[r], 8u, 32);
            const float v1 = __shfl_up(acc1[r], 8u, 32);
            if (same8) { acc0[r] += v0; acc1[r] += v1; }
        }
        const int src16 = __shfl_up(myTgt, 16u, 32);
        const bool same16 = (l31 >= 16) && (src16 == myTgt);
        #pragma unroll
        for (int r = 0; r < 16; ++r) {
            const float v0 = __shfl_up(acc0[r], 16u, 32);
            const float v1 = __shfl_up(acc1[r], 16u, 32);
            if (same16) { acc0[r] += v0; acc1[r] += v1; }
        }
    }
    const int nTgt = __shfl_down(myTgt, 1u, 32);
    const bool validE = (l31 < w);
    return validE && ((l31 == 31) || (nTgt != myTgt));
}

__global__ __launch_bounds__(64 * NWAVES, 1)
void edgenet_kernel(const float* __restrict__ atom,
                    const float* __restrict__ bond,
                    const int*   __restrict__ pair,
                    const float* __restrict__ kern,
                    const float* __restrict__ bias,
                    float* __restrict__ out)
{
    __shared__ __bf16 Blds[64 * PITCH];     // full B [i][k], 140 KB
    __shared__ float  Trow[NWIN][64];       // per-window continuing tail partials
    __shared__ int    Ttag[NWIN];           // tgt tag (INT_MIN = no continuation)

    const int tid  = threadIdx.x;
    const int band = blockIdx.x;
    const int NT   = 64 * NWAVES;

    const int wave = tid >> 6;
    const int lane = tid & 63;
    const int l31  = lane & 31;
    const int half = lane >> 5;
    const int h8   = half * 8;

    // ---- stage B = [kernel | bias] into LDS as bf16 ----
    for (int q = tid; q < (16 * 4096) / 4; q += NT) {
        const int idx = q * 4;                  // flat: b*4096 + i*64 + j
        const int b = idx >> 12;
        const int i = (idx >> 6) & 63;
        const int j = idx & 63;
        const float4 v = *reinterpret_cast<const float4*>(kern + idx);
        bf16x4 w;
        w[0] = (__bf16)v.x; w[1] = (__bf16)v.y; w[2] = (__bf16)v.z; w[3] = (__bf16)v.w;
        *reinterpret_cast<bf16x4*>(Blds + i * PITCH + (b << 6) + j) = w;
    }
    for (int q = tid; q < 4096 / 4; q += NT) {
        const int idx = q * 4;
        const int i = idx >> 6;
        const int j = idx & 63;
        const float4 v = *reinterpret_cast<const float4*>(bias + idx);
        bf16x4 w;
        w[0] = (__bf16)v.x; w[1] = (__bf16)v.y; w[2] = (__bf16)v.z; w[3] = (__bf16)v.w;
        *reinterpret_cast<bf16x4*>(Blds + i * PITCH + 1024 + j) = w;
    }

    // ---- pre-barrier: band bounds + both windows' gathers (overlap staging;
    //      512 thr -> 256-reg budget, ~160 live regs, no spill risk)
    const int r0 = (NR * band) / NBANDS;
    const int r1 = (NR * (band + 1)) / NBANDS;
    int sB, eB;
    first_break2(pair, 32 * r0, 32 * r1, lane, sB, eB);

    const int wiA = 2 * wave, wiB = 2 * wave + 1;
    const int gA = sB + 32 * wiA;
    const int gB = sB + 32 * wiB;
    const int endA = (gA + 32 < eB) ? (gA + 32) : eB;
    const int endB = (gB + 32 < eB) ? (gB + 32) : eB;
    const bool activeA = (gA < eB);
    const bool activeB = (gB < eB);
    const int wA = activeA ? (endA - gA) : 0;
    const int wB = activeB ? (endB - gB) : 0;

    float nbA[4][8], bdA[16]; int tgA;
    float nbB[4][8], bdB[16]; int tgB;
    load_chunk(gA, endA, l31, h8, atom, bond, pair, nbA, bdA, tgA);
    load_chunk(gB, endB, l31, h8, atom, bond, pair, nbB, bdB, tgB);

    __syncthreads();   // staging complete

    const __bf16* __restrict__ Brow0 = Blds + l31 * PITCH;         // features 0..31
    const __bf16* __restrict__ Brow1 = Blds + (32 + l31) * PITCH;  // features 32..63

    f32x16 aA0, aA1, aB0, aB1;   // C[feature][edge]; f=(r&3)+8*(r>>2)+4*half
    #pragma unroll
    for (int r = 0; r < 16; ++r) { aA0[r]=0.f; aA1[r]=0.f; aB0[r]=0.f; aB1[r]=0.f; }

    // ---- ONE pass over B feeds BOTH windows: 2 ds_reads -> 4 MFMAs per t ----
    // main K: k = 16t + 8*half + r ; b = t>>2 ; j = 16*(t&3) + 8*half + r
    #pragma unroll
    for (int t = 0; t < 64; ++t) {
        const int k0 = t * 16 + h8;
        const bf16x8 b0 = *reinterpret_cast<const bf16x8*>(Brow0 + k0);
        const bf16x8 b1 = *reinterpret_cast<const bf16x8*>(Brow1 + k0);
        const float bvA = bdA[t >> 2];
        const float bvB = bdB[t >> 2];
        bf16x8 fa, fb;
        #pragma unroll
        for (int r = 0; r < 8; ++r) fa[r] = (__bf16)(bvA * nbA[t & 3][r]);
        #pragma unroll
        for (int r = 0; r < 8; ++r) fb[r] = (__bf16)(bvB * nbB[t & 3][r]);
        aA0 = __builtin_amdgcn_mfma_f32_32x32x16_bf16(b0, fa, aA0, 0, 0, 0);
        aA1 = __builtin_amdgcn_mfma_f32_32x32x16_bf16(b1, fa, aA1, 0, 0, 0);
        aB0 = __builtin_amdgcn_mfma_f32_32x32x16_bf16(b0, fb, aB0, 0, 0, 0);
        aB1 = __builtin_amdgcn_mfma_f32_32x32x16_bf16(b1, fb, aB1, 0, 0, 0);
    }
    #pragma unroll
    for (int t = 64; t < 68; ++t) {   // bias rows, A-side vector = nbr
        const int k0 = t * 16 + h8;
        const bf16x8 b0 = *reinterpret_cast<const bf16x8*>(Brow0 + k0);
        const bf16x8 b1 = *reinterpret_cast<const bf16x8*>(Brow1 + k0);
        bf16x8 fa, fb;
        #pragma unroll
        for (int r = 0; r < 8; ++r) fa[r] = (__bf16)(nbA[t - 64][r]);
        #pragma unroll
        for (int r = 0; r < 8; ++r) fb[r] = (__bf16)(nbB[t - 64][r]);
        aA0 = __builtin_amdgcn_mfma_f32_32x32x16_bf16(b0, fa, aA0, 0, 0, 0);
        aA1 = __builtin_amdgcn_mfma_f32_32x32x16_bf16(b1, fa, aA1, 0, 0, 0);
        aB0 = __builtin_amdgcn_mfma_f32_32x32x16_bf16(b0, fb, aB0, 0, 0, 0);
        aB1 = __builtin_amdgcn_mfma_f32_32x32x16_bf16(b1, fb, aB1, 0, 0, 0);
    }

    // ---- segmented scans (nb/bd dead now; register pressure relaxes) ----
    const bool lastA = scan_pair(aA0, aA1, tgA, l31, wA);
    const bool lastB = scan_pair(aB0, aB1, tgB, l31, wB);

    // ---- continuation + publish (tail lanes l31==31, both halves) ----
    bool conA = false, conB = false;
    if (activeA && (l31 == 31) && (gA + 32 < eB)) conA = (tgA == pair[2 * (gA + 32)]);
    if (activeB && (l31 == 31) && (gB + 32 < eB)) conB = (tgB == pair[2 * (gB + 32)]);

    if (conA) {
        #pragma unroll
        for (int r = 0; r < 16; ++r) {
            const int f = (r & 3) + 8 * (r >> 2) + 4 * half;
            Trow[wiA][f]      = aA0[r];
            Trow[wiA][32 + f] = aA1[r];
        }
    }
    if (conB) {
        #pragma unroll
        for (int r = 0; r < 16; ++r) {
            const int f = (r & 3) + 8 * (r >> 2) + 4 * half;
            Trow[wiB][f]      = aB0[r];
            Trow[wiB][32 + f] = aB1[r];
        }
    }
    if (lane == 31) {
        Ttag[wiA] = conA ? tgA : INT_MIN;
        Ttag[wiB] = conB ? tgB : INT_MIN;
    }

    __syncthreads();   // Trow/Ttag published

    // ---- emit window A ----
    if (activeA && lastA && !conA) {
        for (int w2 = wiA - 1; w2 >= 0; --w2) {
            if (Ttag[w2] != tgA) break;
            #pragma unroll
            for (int r = 0; r < 16; ++r) {
                const int f = (r & 3) + 8 * (r >> 2) + 4 * half;
                aA0[r] += Trow[w2][f];
                aA1[r] += Trow[w2][32 + f];
            }
        }
        float* o = out + (long)tgA * AD;
        #pragma unroll
        for (int rq = 0; rq < 4; ++rq) {
            float4 v0, v1;
            v0.x = aA0[rq*4+0]; v0.y = aA0[rq*4+1]; v0.z = aA0[rq*4+2]; v0.w = aA0[rq*4+3];
            v1.x = aA1[rq*4+0]; v1.y = aA1[rq*4+1]; v1.z = aA1[rq*4+2]; v1.w = aA1[rq*4+3];
            *reinterpret_cast<float4*>(o + 8 * rq + 4 * half)      = v0;
            *reinterpret_cast<float4*>(o + 32 + 8 * rq + 4 * half) = v1;
        }
    }
    // ---- emit window B ----
    if (activeB && lastB && !conB) {
        for (int w2 = wiB - 1; w2 >= 0; --w2) {
            if (Ttag[w2] != tgB) break;
            #pragma unroll
            for (int r = 0; r < 16; ++r) {
                const int f = (r & 3) + 8 * (r >> 2) + 4 * half;
                aB0[r] += Trow[w2][f];
                aB1[r] += Trow[w2][32 + f];
            }
        }
        float* o = out + (long)tgB * AD;
        #pragma unroll
        for (int rq = 0; rq < 4; ++rq) {
            float4 v0, v1;
            v0.x = aB0[rq*4+0]; v0.y = aB0[rq*4+1]; v0.z = aB0[rq*4+2]; v0.w = aB0[rq*4+3];
            v1.x = aB1[rq*4+0]; v1.y = aB1[rq*4+1]; v1.z = aB1[rq*4+2]; v1.w = aB1[rq*4+3];
            *reinterpret_cast<float4*>(o + 8 * rq + 4 * half)      = v0;
            *reinterpret_cast<float4*>(o + 32 + 8 * rq + 4 * half) = v1;
        }
    }
}

extern "C" void kernel_launch(void* const* d_in, const int* in_sizes, int n_in,
                              void* d_out, int out_size, void* d_ws, size_t ws_size,
                              hipStream_t stream) {
    const float* atom = (const float*)d_in[0];
    const float* bond = (const float*)d_in[1];
    const int*   pair = (const int*)d_in[2];
    const float* kern = (const float*)d_in[3];
    const float* bias = (const float*)d_in[4];
    float* out = (float*)d_out;

    const int n4 = out_size / 4;
    zero_out<<<2048, 256, 0, stream>>>((float4*)out, n4);

    edgenet_kernel<<<NBANDS, 64 * NWAVES, 0, stream>>>(atom, bond, pair, kern, bias, out);
}

// Round 14
// 37.040 us; speedup vs baseline: 1.2672x; 1.2672x over previous
//
#include <hip/hip_runtime.h>
#include <hip/hip_bf16.h>
#include <climits>

#define NATOMS 50000
#define NEDGES 100000
#define AD 64
#define BD 16
#define PITCH 1096            // LDS row pitch in bf16 elems (1088 + 8)
#define NR ((NEDGES + 31) / 32)   // 3125 aligned 32-edge windows
#define NBANDS 256
#define NWAVES 16             // 1024 thr; nW <= 14 windows/band -> 1 window/wave

typedef __bf16 bf16x8 __attribute__((ext_vector_type(8)));
typedef __bf16 bf16x4 __attribute__((ext_vector_type(4)));
typedef float  f32x16 __attribute__((ext_vector_type(16)));

// Dual first_break: smallest break index >= p0 and >= p1, loads overlapped.
// Break: q==0, q==NEDGES, or tgt[q]!=tgt[q-1].
__device__ __forceinline__ void first_break2(const int* __restrict__ pair,
                                             int p0, int p1, const int lane,
                                             int& s, int& e) {
    const int qa = p0 + lane;
    const int qb = p1 + lane;
    const bool ba = (qa == 0 || qa >= NEDGES) ? true : (pair[2 * qa] != pair[2 * qa - 2]);
    const bool bb = (qb == 0 || qb >= NEDGES) ? true : (pair[2 * qb] != pair[2 * qb - 2]);
    const unsigned long long ma = __ballot(ba);
    const unsigned long long mb = __ballot(bb);

    if (ma) { s = p0 + (int)__builtin_ctzll(ma); if (s > NEDGES) s = NEDGES; }
    else {
        int p = p0 + 64;
        while (true) {
            const int q = p + lane;
            const bool bk = (q >= NEDGES) ? true : (pair[2 * q] != pair[2 * q - 2]);
            const unsigned long long m = __ballot(bk);
            if (m) { s = p + (int)__builtin_ctzll(m); if (s > NEDGES) s = NEDGES; break; }
            p += 64;
        }
    }
    if (mb) { e = p1 + (int)__builtin_ctzll(mb); if (e > NEDGES) e = NEDGES; }
    else {
        int p = p1 + 64;
        while (true) {
            const int q = p + lane;
            const bool bk = (q >= NEDGES) ? true : (pair[2 * q] != pair[2 * q - 2]);
            const unsigned long long m = __ballot(bk);
            if (m) { e = p + (int)__builtin_ctzll(m); if (e > NEDGES) e = NEDGES; break; }
            p += 64;
        }
    }
}

// zero cols [half*32, half*32+32) of rows [a0, a1)
__device__ __forceinline__ void zero_rows(float* __restrict__ out,
                                          int a0, int a1, const int half) {
    const float4 z = make_float4(0.f, 0.f, 0.f, 0.f);
    for (int a = a0; a < a1; ++a) {
        float4* o = reinterpret_cast<float4*>(out + (long)a * AD + half * 32);
        #pragma unroll
        for (int rq = 0; rq < 8; ++rq) o[rq] = z;
    }
}

// MFMA + in-wave segmented inclusive scan over window [g, g+32) ∩ [, e)
// for ALL 64 features. C[feature][edge], edge = l31; acc0 = features 0..31,
// acc1 = features 32..63, f = (r&3)+8*(r>>2)+4*half (+32 for acc1).
__device__ __forceinline__ void scan_slot(
    const int g, const int e,
    const float* __restrict__ atom, const float* __restrict__ bond,
    const int* __restrict__ pair,
    const __bf16* __restrict__ Brow0, const __bf16* __restrict__ Brow1,
    const int l31, const int half, const int h8,
    f32x16& acc0, f32x16& acc1, int& myTgt, bool& isLast)
{
    const int eA = g + l31;
    const bool validE = (eA < e);
    const int eAc = validE ? eA : 0;

    int ni = pair[2 * eAc + 1];
    if ((unsigned)ni >= NATOMS) ni = 0;
    const float* nbrRow  = atom + (long)ni * AD;
    const float* bondRow = bond + (long)eAc * BD;

    // half-row of nbr this lane needs: j = 16q + 8*half + r
    // (invalid lanes' garbage is never consumed: tgt=INT_MAX never matches)
    float nb[4][8];
    #pragma unroll
    for (int q = 0; q < 4; ++q) {
        const float4 lo = *reinterpret_cast<const float4*>(nbrRow + q * 16 + h8);
        const float4 hi = *reinterpret_cast<const float4*>(nbrRow + q * 16 + h8 + 4);
        nb[q][0] = lo.x; nb[q][1] = lo.y; nb[q][2] = lo.z; nb[q][3] = lo.w;
        nb[q][4] = hi.x; nb[q][5] = hi.y; nb[q][6] = hi.z; nb[q][7] = hi.w;
    }
    float bd[16];
    #pragma unroll
    for (int q = 0; q < 4; ++q) {
        const float4 v = *reinterpret_cast<const float4*>(bondRow + q * 4);
        bd[q * 4 + 0] = v.x; bd[q * 4 + 1] = v.y;
        bd[q * 4 + 2] = v.z; bd[q * 4 + 3] = v.w;
    }

    #pragma unroll
    for (int r = 0; r < 16; ++r) { acc0[r] = 0.f; acc1[r] = 0.f; }

    // main K: k = 16t + 8*half + r ; b = t>>2 ; j = 16*(t&3) + 8*half + r
    // ONE a-fragment feeds BOTH feature-half MFMAs.
    #pragma unroll
    for (int t = 0; t < 64; ++t) {
        const float bv = bd[t >> 2];
        bf16x8 a;
        #pragma unroll
        for (int r = 0; r < 8; ++r) a[r] = (__bf16)(bv * nb[t & 3][r]);
        const int k0 = t * 16 + h8;
        const bf16x8 b0 = *reinterpret_cast<const bf16x8*>(Brow0 + k0);
        const bf16x8 b1 = *reinterpret_cast<const bf16x8*>(Brow1 + k0);
        acc0 = __builtin_amdgcn_mfma_f32_32x32x16_bf16(b0, a, acc0, 0, 0, 0);
        acc1 = __builtin_amdgcn_mfma_f32_32x32x16_bf16(b1, a, acc1, 0, 0, 0);
    }
    #pragma unroll
    for (int t = 64; t < 68; ++t) {   // bias rows, A-side vector = nbr
        bf16x8 a;
        #pragma unroll
        for (int r = 0; r < 8; ++r) a[r] = (__bf16)(nb[t - 64][r]);
        const int k0 = t * 16 + h8;
        const bf16x8 b0 = *reinterpret_cast<const bf16x8*>(Brow0 + k0);
        const bf16x8 b1 = *reinterpret_cast<const bf16x8*>(Brow1 + k0);
        acc0 = __builtin_amdgcn_mfma_f32_32x32x16_bf16(b0, a, acc0, 0, 0, 0);
        acc1 = __builtin_amdgcn_mfma_f32_32x32x16_bf16(b1, a, acc1, 0, 0, 0);
    }

    // segmented inclusive scan over sorted tgt within the 32-lane group.
    // Steps 1,2,4 always; steps 8,16 only if some segment length >= 9.
    myTgt = validE ? pair[2 * eA] : INT_MAX;
    #pragma unroll
    for (int d = 1; d <= 4; d <<= 1) {
        const int srcTgt = __shfl_up(myTgt, (unsigned)d, 32);
        const bool same = (l31 >= d) && (srcTgt == myTgt);
        #pragma unroll
        for (int r = 0; r < 16; ++r) {
            const float v0 = __shfl_up(acc0[r], (unsigned)d, 32);
            const float v1 = __shfl_up(acc1[r], (unsigned)d, 32);
            if (same) { acc0[r] += v0; acc1[r] += v1; }
        }
    }
    const int src8 = __shfl_up(myTgt, 8u, 32);
    if (__any((l31 >= 8) && (src8 == myTgt))) {
        const bool same8 = (l31 >= 8) && (src8 == myTgt);
        #pragma unroll
        for (int r = 0; r < 16; ++r) {
            const float v0 = __shfl_up(acc0[r], 8u, 32);
            const float v1 = __shfl_up(acc1[r], 8u, 32);
            if (same8) { acc0[r] += v0; acc1[r] += v1; }
        }
        const int src16 = __shfl_up(myTgt, 16u, 32);
        const bool same16 = (l31 >= 16) && (src16 == myTgt);
        #pragma unroll
        for (int r = 0; r < 16; ++r) {
            const float v0 = __shfl_up(acc0[r], 16u, 32);
            const float v1 = __shfl_up(acc1[r], 16u, 32);
            if (same16) { acc0[r] += v0; acc1[r] += v1; }
        }
    }

    const int nTgt = __shfl_down(myTgt, 1u, 32);
    isLast = validE && ((l31 == 31) || (nTgt != myTgt));
}

__global__ __launch_bounds__(64 * NWAVES, 1)
void edgenet_kernel(const float* __restrict__ atom,
                    const float* __restrict__ bond,
                    const int*   __restrict__ pair,
                    const float* __restrict__ kern,
                    const float* __restrict__ bias,
                    float* __restrict__ out)
{
    __shared__ __bf16 Blds[64 * PITCH];     // full B [i][k], 140 KB
    __shared__ float  Trow[NWAVES][64];     // per-window continuing tail partials
    __shared__ int    Ttag[NWAVES];         // tgt tag (INT_MIN = no continuation)

    const int tid  = threadIdx.x;
    const int band = blockIdx.x;
    const int NT   = 64 * NWAVES;

    const int wave = tid >> 6;
    const int lane = tid & 63;
    const int l31  = lane & 31;
    const int half = lane >> 5;
    const int h8   = half * 8;

    // ---- stage B = [kernel | bias] into LDS as bf16 ----
    for (int q = tid; q < (16 * 4096) / 4; q += NT) {
        const int idx = q * 4;                  // flat: b*4096 + i*64 + j
        const int b = idx >> 12;
        const int i = (idx >> 6) & 63;
        const int j = idx & 63;
        const float4 v = *reinterpret_cast<const float4*>(kern + idx);
        bf16x4 w;
        w[0] = (__bf16)v.x; w[1] = (__bf16)v.y; w[2] = (__bf16)v.z; w[3] = (__bf16)v.w;
        *reinterpret_cast<bf16x4*>(Blds + i * PITCH + (b << 6) + j) = w;
    }
    {   // bias: exactly 1024 quads
        const int q = tid;
        const int idx = q * 4;
        const int i = idx >> 6;
        const int j = idx & 63;
        const float4 v = *reinterpret_cast<const float4*>(bias + idx);
        bf16x4 w;
        w[0] = (__bf16)v.x; w[1] = (__bf16)v.y; w[2] = (__bf16)v.z; w[3] = (__bf16)v.w;
        *reinterpret_cast<bf16x4*>(Blds + i * PITCH + 1024 + j) = w;
    }

    // ---- pre-barrier: segment-aligned band bounds (2 ints live, no spill risk)
    const int r0 = (NR * band) / NBANDS;
    const int r1 = (NR * (band + 1)) / NBANDS;
    int sB, eB;
    first_break2(pair, 32 * r0, 32 * r1, lane, sB, eB);

    __syncthreads();   // staging complete

    const __bf16* __restrict__ Brow0 = Blds + l31 * PITCH;         // features 0..31
    const __bf16* __restrict__ Brow1 = Blds + (32 + l31) * PITCH;  // features 32..63

    // wave w owns the fixed aligned window [g, gEnd)
    const int g    = sB + 32 * wave;
    const int gEnd = (g + 32 < eB) ? (g + 32) : eB;
    const bool active = (g < eB);
    const int wW = active ? (gEnd - g) : 0;

    f32x16 acc0, acc1;
    int myTgt = INT_MAX;
    bool isLast = false;

    if (active) {
        scan_slot(g, gEnd, atom, bond, pair, Brow0, Brow1,
                  l31, half, h8, acc0, acc1, myTgt, isLast);
    }

    // continuation into next window? (tail lanes l31==31 only; truncated
    // windows have g+32 >= eB so contin=false automatically)
    bool myContin = false;
    if (active && (l31 == 31) && (g + 32 < eB)) {
        myContin = (myTgt == pair[2 * (g + 32)]);
    }

    // tail lanes of continuing windows stash their window-partial row
    if (myContin) {
        #pragma unroll
        for (int r = 0; r < 16; ++r) {
            const int f = (r & 3) + 8 * (r >> 2) + 4 * half;
            Trow[wave][f]      = acc0[r];
            Trow[wave][32 + f] = acc1[r];
        }
    }
    if (lane == 31) Ttag[wave] = myContin ? myTgt : INT_MIN;   // also inactive waves

    __syncthreads();   // Trow/Ttag published

    const bool validE = (l31 < wW);

    // ---- fused zeroing of gap rows (atoms with no incoming edges). ----
    // Windows tile the edge range contiguously (across waves AND bands), so
    // the seg-FIRST lane of each segment exclusively owns the gap before it.
    if (active && validE) {
        const int pTgt = __shfl_up(myTgt, 1u, 32);
        const bool segFirst = (l31 == 0) || (pTgt != myTgt);
        if (segFirst) {
            const int prevEdgeTgt = (l31 > 0) ? pTgt
                                  : ((g > 0) ? pair[2 * (g - 1)] : -1);
            // continuation windows: prevEdgeTgt == myTgt -> empty range
            if (prevEdgeTgt + 1 < myTgt)
                zero_rows(out, prevEdgeTgt + 1, myTgt, half);
        }
        // tail gap after the globally last edge
        if (g + l31 == NEDGES - 1 && myTgt + 1 < NATOMS)
            zero_rows(out, myTgt + 1, NATOMS, half);
    }

    // ---- emit owned segments ----
    if (active && isLast && !myContin) {
        // merge tails from earlier windows covered by my segment
        for (int w2 = wave - 1; w2 >= 0; --w2) {
            if (Ttag[w2] != myTgt) break;
            #pragma unroll
            for (int r = 0; r < 16; ++r) {
                const int f = (r & 3) + 8 * (r >> 2) + 4 * half;
                acc0[r] += Trow[w2][f];
                acc1[r] += Trow[w2][32 + f];
            }
        }
        float* o = out + (long)myTgt * AD;
        #pragma unroll
        for (int rq = 0; rq < 4; ++rq) {
            float4 v0, v1;
            v0.x = acc0[rq*4+0]; v0.y = acc0[rq*4+1]; v0.z = acc0[rq*4+2]; v0.w = acc0[rq*4+3];
            v1.x = acc1[rq*4+0]; v1.y = acc1[rq*4+1]; v1.z = acc1[rq*4+2]; v1.w = acc1[rq*4+3];
            *reinterpret_cast<float4*>(o + 8 * rq + 4 * half)      = v0;
            *reinterpret_cast<float4*>(o + 32 + 8 * rq + 4 * half) = v1;
        }
    }
}

extern "C" void kernel_launch(void* const* d_in, const int* in_sizes, int n_in,
                              void* d_out, int out_size, void* d_ws, size_t ws_size,
                              hipStream_t stream) {
    const float* atom = (const float*)d_in[0];
    const float* bond = (const float*)d_in[1];
    const int*   pair = (const int*)d_in[2];
    const float* kern = (const float*)d_in[3];
    const float* bias = (const float*)d_in[4];
    float* out = (float*)d_out;

    // no memset: gap rows are zeroed in-kernel; covered rows are owner-written
    edgenet_kernel<<<NBANDS, 64 * NWAVES, 0, stream>>>(atom, bond, pair, kern, bias, out);
}